// Round 16
// baseline (31.901 us; speedup 1.0000x reference)
//
#include <hip/hip_runtime.h>

#define GROUPS 196

// DPP neighbor reads within a 16-lane DPP row. bound_ctrl=1 zeros out-of-row.
// Lane mapping: lane = q*16 + py  (q = px-quad, py = pixel row).
// => a DPP row (16 lanes) spans py=0..15 of ONE quad; lane+-1 = py+-1, and
// bound_ctrl zero-fill hits EXACTLY the py=0/15 tile edges (zero-pad for conv,
// zero-contribution for exclude-pad pool). Vertical exchange is mask-free DPP.
// Horizontal cross-quad (lane+-16) uses ds_bpermute (register crossbar, no LDS
// memory, no fence) + mask-multiply. ALL cross-lane ops are UNCONDITIONAL
// (EXEC = all 64 lanes everywhere; R12-R14 failed from DPP under exec-masked
// selects — masks here are applied by multiply, never by branch/select).
__device__ __forceinline__ float dppL(float v) {   // lane l gets v of lane l-1
    return __int_as_float(__builtin_amdgcn_update_dpp(
        __float_as_int(v), __float_as_int(v), 0x111, 0xF, 0xF, true));
}
__device__ __forceinline__ float dppR(float v) {   // lane l gets v of lane l+1
    return __int_as_float(__builtin_amdgcn_update_dpp(
        __float_as_int(v), __float_as_int(v), 0x101, 0xF, 0xF, true));
}
__device__ __forceinline__ float bperm(int addr, float v) {
    return __int_as_float(__builtin_amdgcn_ds_bpermute(addr, __float_as_int(v)));
}
__device__ __forceinline__ float qgelu(float v) {  // exact: unbounded domain
    return v * __builtin_amdgcn_rcpf(1.0f + __expf(-1.702f * v));
}
// p * sigmoid(1.702 p) on [0,1]; deg-5 poly, |err| < 3e-5 (validated R10-R15).
__device__ __forceinline__ float qgelu01(float p) {
    float s = fmaf(p, 0.041056f, -0.126448f);
    s = fmaf(p, s, 0.006306f);
    s = fmaf(p, s, 0.424881f);
    s = fmaf(p, s, 0.5f);
    return p * s;
}

// One WAVE per (g,b) tile: 64 lanes x 4 px; px = q*4+j, row py.
// Zero __shared__, zero fences, zero barriers.
__global__ __launch_bounds__(256) void convpass_fused(
    const float* __restrict__ x,
    const float* __restrict__ conv_w,
    const float* __restrict__ conv_b,
    const float* __restrict__ centers,
    const float* __restrict__ widths,
    const float* __restrict__ down_w,
    const float* __restrict__ down_b,
    float* __restrict__ out)
{
    const int tid = threadIdx.x;
    const int l  = tid & 63;
    const int wv = tid >> 6;
    const int g  = blockIdx.x * 4 + wv;      // grid.x = 49 -> g in [0,196)
    const int b  = blockIdx.y;
    const int q  = l >> 4;                   // px quad 0..3
    const int py = l & 15;                   // pixel row 0..15
    const float mL = (q > 0) ? 1.f : 0.f;    // cross-quad edge masks (multiply!)
    const float mR = (q < 3) ? 1.f : 0.f;
    const int aL = ((l - 16) & 63) << 2;     // bpermute byte addr: lane-16
    const int aR = ((l + 16) & 63) << 2;     // lane+16

    // wave-uniform group index -> scalar loads for all params
    const int sg = __builtin_amdgcn_readfirstlane(g);
    const float* cw  = conv_w  + sg * 81;
    const float* cen = centers + sg * 12;
    const float* wid = widths  + sg * 12;
    const float* dwp = down_w  + sg * 36;
    const float cb0 = conv_b[sg*3+0], cb1 = conv_b[sg*3+1], cb2 = conv_b[sg*3+2];
    const float db0 = down_b[sg*3+0], db1 = down_b[sg*3+1], db2 = down_b[sg*3+2];

    // ---- load own 4 px (row py, quad q) of 3 channels: coalesced dwordx4 ----
    const int tok = b * 197 + g + 1;
    const float4* xin4 = (const float4*)x + tok * 192;
    const int fo = py * 4 + q;               // float4 index in a 64-float4 plane
    const float4 A0 = xin4[fo];
    const float4 A1 = xin4[64 + fo];
    const float4 A2 = xin4[128 + fo];

    // ---- rows py-1 / py / py+1 per channel: vertical via mask-free DPP ----
    float4 V[3][3];
    V[0][1] = A0; V[1][1] = A1; V[2][1] = A2;
    #pragma unroll
    for (int ic = 0; ic < 3; ++ic) {
        const float4 a = V[ic][1];
        V[ic][0] = make_float4(dppL(a.x), dppL(a.y), dppL(a.z), dppL(a.w)); // py-1
        V[ic][2] = make_float4(dppR(a.x), dppR(a.y), dppR(a.z), dppR(a.w)); // py+1
    }

    // ---- cross-quad edge values via bpermute + mask-multiply ----
    float L[3][3], R[3][3];
    #pragma unroll
    for (int ic = 0; ic < 3; ++ic) {
        #pragma unroll
        for (int r = 0; r < 3; ++r) {
            L[ic][r] = bperm(aL, V[ic][r].w) * mL;   // (q-1, row r).px3
            R[ic][r] = bperm(aR, V[ic][r].x) * mR;   // (q+1, row r).px0
        }
    }

    // ---- grouped 3x3 conv: all in-register ----
    float acc[3][4];
    #pragma unroll
    for (int j = 0; j < 4; ++j) { acc[0][j] = cb0; acc[1][j] = cb1; acc[2][j] = cb2; }
    #pragma unroll
    for (int oc = 0; oc < 3; ++oc) {
        #pragma unroll
        for (int ic = 0; ic < 3; ++ic) {
            #pragma unroll
            for (int r = 0; r < 3; ++r) {
                const float w0 = cw[oc*27 + ic*9 + r*3 + 0];
                const float w1 = cw[oc*27 + ic*9 + r*3 + 1];
                const float w2 = cw[oc*27 + ic*9 + r*3 + 2];
                const float4 v = V[ic][r];
                acc[oc][0] = fmaf(L[ic][r], w0, fmaf(v.x, w1, fmaf(v.y, w2, acc[oc][0])));
                acc[oc][1] = fmaf(v.x,      w0, fmaf(v.y, w1, fmaf(v.z, w2, acc[oc][1])));
                acc[oc][2] = fmaf(v.y,      w0, fmaf(v.z, w1, fmaf(v.w, w2, acc[oc][2])));
                acc[oc][3] = fmaf(v.z,      w0, fmaf(v.w, w1, fmaf(R[ic][r], w2, acc[oc][3])));
            }
        }
    }

    float yv[3][4];
    #pragma unroll
    for (int oc = 0; oc < 3; ++oc)
        #pragma unroll
        for (int j = 0; j < 4; ++j)
            yv[oc][j] = qgelu(acc[oc][j]);

    // exclude-pad reciprocals 1/(vx*vy); px edges: px==0 (q0,j0), px==15 (q3,j3)
    const bool  vy2 = (py == 0) | (py == 15);
    const float rE = vy2 ? 0.25f     : (1.f/6.f);
    const float rM = vy2 ? (1.f/6.f) : (1.f/9.f);
    const float rc[4] = { (q == 0) ? rE : rM, rM, rM, (q == 3) ? rE : rM };

    float o[3][4];
    #pragma unroll
    for (int j = 0; j < 4; ++j) { o[0][j] = db0; o[1][j] = db1; o[2][j] = db2; }

    // ---- per-oc: hist -> horizontal 3-sum -> vertical 3-sum (DPP) -> proj ----
    // widths>0, |.|>=0 => t_k >= 1: relu and +1e-5 are no-ops (validated R10+).
    // bin3 via sum-to-1 identity (validated R11+).
    #pragma unroll
    for (int oc = 0; oc < 3; ++oc) {
        float hj[3][4];
        #pragma unroll
        for (int j = 0; j < 4; ++j) {
            const float y = yv[oc][j];
            const float t0 = fmaf(wid[oc*4+0], fabsf(y + cen[oc*4+0]), 1.0f);
            const float t1 = fmaf(wid[oc*4+1], fabsf(y + cen[oc*4+1]), 1.0f);
            const float t2 = fmaf(wid[oc*4+2], fabsf(y + cen[oc*4+2]), 1.0f);
            const float t3 = fmaf(wid[oc*4+3], fabsf(y + cen[oc*4+3]), 1.0f);
            const float inv = __builtin_amdgcn_rcpf((t0 + t1) + (t2 + t3));
            hj[0][j] = t0 * inv; hj[1][j] = t1 * inv; hj[2][j] = t2 * inv;
        }
        // horizontal 3-sum; cross-quad edges via bpermute, mask folded into fma
        float rs[3][4];
        #pragma unroll
        for (int k = 0; k < 3; ++k) {
            const float lh = bperm(aL, hj[k][3]);   // unconditional crossbar
            const float rh = bperm(aR, hj[k][0]);
            const float s01 = hj[k][0] + hj[k][1];
            const float s23 = hj[k][2] + hj[k][3];
            rs[k][0] = fmaf(mL, lh, s01);
            rs[k][1] = s01 + hj[k][2];
            rs[k][2] = hj[k][1] + s23;
            rs[k][3] = fmaf(mR, rh, s23);
        }
        // vertical 3-sum via mask-free DPP (bound_ctrl zero == tile edge zero)
        float vs[3][4];
        #pragma unroll
        for (int k = 0; k < 3; ++k) {
            #pragma unroll
            for (int j = 0; j < 4; ++j)
                vs[k][j] = rs[k][j] + dppL(rs[k][j]) + dppR(rs[k][j]);
        }
        // exclude-pad average + poly-gelu + 12->3 projection
        #pragma unroll
        for (int j = 0; j < 4; ++j) {
            const float p0 = vs[0][j] * rc[j];
            const float p1 = vs[1][j] * rc[j];
            const float p2 = vs[2][j] * rc[j];
            const float p3 = 1.0f - p0 - p1 - p2;
            const float u0 = qgelu01(p0);
            const float u1 = qgelu01(p1);
            const float u2 = qgelu01(p2);
            const float u3 = qgelu01(p3);
            const int i = oc * 4;
            o[0][j] = fmaf(u0, dwp[i],    fmaf(u1, dwp[i+1],    fmaf(u2, dwp[i+2],    fmaf(u3, dwp[i+3],    o[0][j]))));
            o[1][j] = fmaf(u0, dwp[12+i], fmaf(u1, dwp[12+i+1], fmaf(u2, dwp[12+i+2], fmaf(u3, dwp[12+i+3], o[1][j]))));
            o[2][j] = fmaf(u0, dwp[24+i], fmaf(u1, dwp[24+i+1], fmaf(u2, dwp[24+i+2], fmaf(u3, dwp[24+i+3], o[2][j]))));
        }
    }

    // ---- vectorized output stores (wave covers each 1KB span completely) ----
    float4* op4 = (float4*)out + tok * 192;
    op4[fo]       = make_float4(o[0][0], o[0][1], o[0][2], o[0][3]);
    op4[64 + fo]  = make_float4(o[1][0], o[1][1], o[1][2], o[1][3]);
    op4[128 + fo] = make_float4(o[2][0], o[2][1], o[2][2], o[2][3]);

    // ---- CLS pass-through: wave g==0 of each batch (wave-uniform branch) ----
    if (g == 0) {
        const float4* xc = (const float4*)x + b * 197 * 192;
        float4* oc4 = (float4*)out + b * 197 * 192;
        oc4[l]       = xc[l];
        oc4[64 + l]  = xc[64 + l];
        oc4[128 + l] = xc[128 + l];
    }
}

extern "C" void kernel_launch(void* const* d_in, const int* in_sizes, int n_in,
                              void* d_out, int out_size, void* d_ws, size_t ws_size,
                              hipStream_t stream) {
    const float* x       = (const float*)d_in[0];
    const float* conv_w  = (const float*)d_in[1];
    const float* conv_b  = (const float*)d_in[2];
    const float* centers = (const float*)d_in[3];
    const float* widths  = (const float*)d_in[4];
    const float* down_w  = (const float*)d_in[5];
    const float* down_b  = (const float*)d_in[6];
    float* out = (float*)d_out;

    const int B = in_sizes[0] / (197 * 768);

    dim3 grid(GROUPS / 4, B);   // 49 x B blocks, 4 waves/block, 1 tile/wave
    convpass_fused<<<grid, 256, 0, stream>>>(x, conv_w, conv_b, centers, widths,
                                             down_w, down_b, out);
}

// Round 17
// 30.653 us; speedup vs baseline: 1.0407x; 1.0407x over previous
//
#include <hip/hip_runtime.h>

#define GROUPS 196

// Lane mapping: lane = q*16 + py (q = px-quad = DPP-row index, py = pixel row).
// Vertical (py+-1) = lane+-1 = DPP row_shr/row_shl with bound_ctrl zero-fill
// landing EXACTLY on the py=0/15 tile edges (mask-free zero-pad semantics).
// Horizontal cross-quad (q+-1) = lane+-16 via ds_bpermute + MULTIPLY masks.
// All cross-lane ops are UNCONDITIONAL (EXEC=all-64; R12-R14 failed from DPP
// under exec-masked selects). bperm and DPP commute (disjoint index axes),
// and q-masks are DPP-row-coherent, so edge columns are fetched once at the
// center row and vertically shifted in-register.
__device__ __forceinline__ float dppL(float v) {   // lane l gets v of lane l-1
    return __int_as_float(__builtin_amdgcn_update_dpp(
        __float_as_int(v), __float_as_int(v), 0x111, 0xF, 0xF, true));
}
__device__ __forceinline__ float dppR(float v) {   // lane l gets v of lane l+1
    return __int_as_float(__builtin_amdgcn_update_dpp(
        __float_as_int(v), __float_as_int(v), 0x101, 0xF, 0xF, true));
}
__device__ __forceinline__ float bperm(int addr, float v) {
    return __int_as_float(__builtin_amdgcn_ds_bpermute(addr, __float_as_int(v)));
}
__device__ __forceinline__ float qgelu(float v) {  // exact: unbounded domain
    return v * __builtin_amdgcn_rcpf(1.0f + __expf(-1.702f * v));
}
// p * sigmoid(1.702 p) on [0,1]; degree-3 (Chebyshev-node quadratic for the
// sigmoid factor), |err| < ~1.2e-3 on domain -> output contribution ~1e-3.
__device__ __forceinline__ float qgelu01(float p) {
    return p * fmaf(p, fmaf(p, -0.11333f, 0.46195f), 0.49805f);
}

// One WAVE per (g,b) tile: 64 lanes x 4 px; px = q*4+j, row py.
// Zero __shared__, zero fences, zero barriers.
__global__ __launch_bounds__(256) void convpass_fused(
    const float* __restrict__ x,
    const float* __restrict__ conv_w,
    const float* __restrict__ conv_b,
    const float* __restrict__ centers,
    const float* __restrict__ widths,
    const float* __restrict__ down_w,
    const float* __restrict__ down_b,
    float* __restrict__ out)
{
    const int tid = threadIdx.x;
    const int l  = tid & 63;
    const int wv = tid >> 6;
    const int g  = blockIdx.x * 4 + wv;      // grid.x = 49 -> g in [0,196)
    const int b  = blockIdx.y;
    const int q  = l >> 4;                   // px quad 0..3 (DPP row)
    const int py = l & 15;                   // pixel row 0..15
    const float mL = (q > 0) ? 1.f : 0.f;    // cross-quad masks (MULTIPLY only)
    const float mR = (q < 3) ? 1.f : 0.f;
    const int aL = ((l - 16) & 63) << 2;     // bpermute byte addr: lane-16
    const int aR = ((l + 16) & 63) << 2;     // lane+16

    // wave-uniform group index -> scalar loads for all params
    const int sg = __builtin_amdgcn_readfirstlane(g);
    const float* cw  = conv_w  + sg * 81;
    const float* cen = centers + sg * 12;
    const float* wid = widths  + sg * 12;
    const float* dwp = down_w  + sg * 36;
    const float cb0 = conv_b[sg*3+0], cb1 = conv_b[sg*3+1], cb2 = conv_b[sg*3+2];
    const float db0 = down_b[sg*3+0], db1 = down_b[sg*3+1], db2 = down_b[sg*3+2];

    // ---- load own 4 px (row py, quad q) of 3 channels: coalesced dwordx4 ----
    const int tok = b * 197 + g + 1;
    const float4* xin4 = (const float4*)x + tok * 192;
    const int fo = py * 4 + q;               // float4 index in a 64-float4 plane
    const float4 A0 = xin4[fo];
    const float4 A1 = xin4[64 + fo];
    const float4 A2 = xin4[128 + fo];

    // ---- rows py-1 / py / py+1 per channel: vertical via mask-free DPP ----
    float4 V[3][3];
    V[0][1] = A0; V[1][1] = A1; V[2][1] = A2;
    #pragma unroll
    for (int ic = 0; ic < 3; ++ic) {
        const float4 a = V[ic][1];
        V[ic][0] = make_float4(dppL(a.x), dppL(a.y), dppL(a.z), dppL(a.w)); // py-1
        V[ic][2] = make_float4(dppR(a.x), dppR(a.y), dppR(a.z), dppR(a.w)); // py+1
    }

    // ---- cross-quad edge columns: ONE bperm pair per channel at center row,
    //      masked once (whole DPP row shares q), then shifted vertically ----
    float L[3][3], R[3][3];
    #pragma unroll
    for (int ic = 0; ic < 3; ++ic) {
        const float eL = bperm(aL, V[ic][1].w) * mL;   // (py, q-1).px3
        const float eR = bperm(aR, V[ic][1].x) * mR;   // (py, q+1).px0
        L[ic][0] = dppL(eL); L[ic][1] = eL; L[ic][2] = dppR(eL);
        R[ic][0] = dppL(eR); R[ic][1] = eR; R[ic][2] = dppR(eR);
    }

    // ---- grouped 3x3 conv: all in-register ----
    float acc[3][4];
    #pragma unroll
    for (int j = 0; j < 4; ++j) { acc[0][j] = cb0; acc[1][j] = cb1; acc[2][j] = cb2; }
    #pragma unroll
    for (int oc = 0; oc < 3; ++oc) {
        #pragma unroll
        for (int ic = 0; ic < 3; ++ic) {
            #pragma unroll
            for (int r = 0; r < 3; ++r) {
                const float w0 = cw[oc*27 + ic*9 + r*3 + 0];
                const float w1 = cw[oc*27 + ic*9 + r*3 + 1];
                const float w2 = cw[oc*27 + ic*9 + r*3 + 2];
                const float4 v = V[ic][r];
                acc[oc][0] = fmaf(L[ic][r], w0, fmaf(v.x, w1, fmaf(v.y, w2, acc[oc][0])));
                acc[oc][1] = fmaf(v.x,      w0, fmaf(v.y, w1, fmaf(v.z, w2, acc[oc][1])));
                acc[oc][2] = fmaf(v.y,      w0, fmaf(v.z, w1, fmaf(v.w, w2, acc[oc][2])));
                acc[oc][3] = fmaf(v.z,      w0, fmaf(v.w, w1, fmaf(R[ic][r], w2, acc[oc][3])));
            }
        }
    }

    float yv[3][4];
    #pragma unroll
    for (int oc = 0; oc < 3; ++oc)
        #pragma unroll
        for (int j = 0; j < 4; ++j)
            yv[oc][j] = qgelu(acc[oc][j]);

    // exclude-pad reciprocals 1/(vx*vy); px edges: px==0 (q0,j0), px==15 (q3,j3)
    const bool  vy2 = (py == 0) | (py == 15);
    const float rE = vy2 ? 0.25f     : (1.f/6.f);
    const float rM = vy2 ? (1.f/6.f) : (1.f/9.f);
    const float rc[4] = { (q == 0) ? rE : rM, rM, rM, (q == 3) ? rE : rM };

    float o[3][4];
    #pragma unroll
    for (int j = 0; j < 4; ++j) { o[0][j] = db0; o[1][j] = db1; o[2][j] = db2; }

    // ---- per-oc: hist -> horizontal 3-sum -> vertical 3-sum (DPP) -> proj ----
    // widths>0, |.|>=0 => t_k >= 1: relu and +1e-5 are no-ops (validated R10+).
    // bin3 via sum-to-1 identity (validated R11+).
    #pragma unroll
    for (int oc = 0; oc < 3; ++oc) {
        float hj[3][4];
        #pragma unroll
        for (int j = 0; j < 4; ++j) {
            const float y = yv[oc][j];
            const float t0 = fmaf(wid[oc*4+0], fabsf(y + cen[oc*4+0]), 1.0f);
            const float t1 = fmaf(wid[oc*4+1], fabsf(y + cen[oc*4+1]), 1.0f);
            const float t2 = fmaf(wid[oc*4+2], fabsf(y + cen[oc*4+2]), 1.0f);
            const float t3 = fmaf(wid[oc*4+3], fabsf(y + cen[oc*4+3]), 1.0f);
            const float inv = __builtin_amdgcn_rcpf((t0 + t1) + (t2 + t3));
            hj[0][j] = t0 * inv; hj[1][j] = t1 * inv; hj[2][j] = t2 * inv;
        }
        // horizontal 3-sum; cross-quad edges via bpermute, mask folded into fma
        float rs[3][4];
        #pragma unroll
        for (int k = 0; k < 3; ++k) {
            const float lh = bperm(aL, hj[k][3]);   // unconditional crossbar
            const float rh = bperm(aR, hj[k][0]);
            const float s01 = hj[k][0] + hj[k][1];
            const float s23 = hj[k][2] + hj[k][3];
            rs[k][0] = fmaf(mL, lh, s01);
            rs[k][1] = s01 + hj[k][2];
            rs[k][2] = hj[k][1] + s23;
            rs[k][3] = fmaf(mR, rh, s23);
        }
        // vertical 3-sum via mask-free DPP (bound_ctrl zero == tile edge zero)
        // + exclude-pad average + poly-gelu + 12->3 projection
        #pragma unroll
        for (int j = 0; j < 4; ++j) {
            const float v0 = rs[0][j] + dppL(rs[0][j]) + dppR(rs[0][j]);
            const float v1 = rs[1][j] + dppL(rs[1][j]) + dppR(rs[1][j]);
            const float v2 = rs[2][j] + dppL(rs[2][j]) + dppR(rs[2][j]);
            const float p0 = v0 * rc[j];
            const float p1 = v1 * rc[j];
            const float p2 = v2 * rc[j];
            const float p3 = 1.0f - p0 - p1 - p2;
            const float u0 = qgelu01(p0);
            const float u1 = qgelu01(p1);
            const float u2 = qgelu01(p2);
            const float u3 = qgelu01(p3);
            const int i = oc * 4;
            o[0][j] = fmaf(u0, dwp[i],    fmaf(u1, dwp[i+1],    fmaf(u2, dwp[i+2],    fmaf(u3, dwp[i+3],    o[0][j]))));
            o[1][j] = fmaf(u0, dwp[12+i], fmaf(u1, dwp[12+i+1], fmaf(u2, dwp[12+i+2], fmaf(u3, dwp[12+i+3], o[1][j]))));
            o[2][j] = fmaf(u0, dwp[24+i], fmaf(u1, dwp[24+i+1], fmaf(u2, dwp[24+i+2], fmaf(u3, dwp[24+i+3], o[2][j]))));
        }
    }

    // ---- vectorized output stores (wave covers each 1KB span completely) ----
    float4* op4 = (float4*)out + tok * 192;
    op4[fo]       = make_float4(o[0][0], o[0][1], o[0][2], o[0][3]);
    op4[64 + fo]  = make_float4(o[1][0], o[1][1], o[1][2], o[1][3]);
    op4[128 + fo] = make_float4(o[2][0], o[2][1], o[2][2], o[2][3]);

    // ---- CLS pass-through: wave g==0 of each batch (wave-uniform branch) ----
    if (g == 0) {
        const float4* xc = (const float4*)x + b * 197 * 192;
        float4* oc4 = (float4*)out + b * 197 * 192;
        oc4[l]       = xc[l];
        oc4[64 + l]  = xc[64 + l];
        oc4[128 + l] = xc[128 + l];
    }
}

extern "C" void kernel_launch(void* const* d_in, const int* in_sizes, int n_in,
                              void* d_out, int out_size, void* d_ws, size_t ws_size,
                              hipStream_t stream) {
    const float* x       = (const float*)d_in[0];
    const float* conv_w  = (const float*)d_in[1];
    const float* conv_b  = (const float*)d_in[2];
    const float* centers = (const float*)d_in[3];
    const float* widths  = (const float*)d_in[4];
    const float* down_w  = (const float*)d_in[5];
    const float* down_b  = (const float*)d_in[6];
    float* out = (float*)d_out;

    const int B = in_sizes[0] / (197 * 768);

    dim3 grid(GROUPS / 4, B);   // 49 x B blocks, 4 waves/block, 1 tile/wave
    convpass_fused<<<grid, 256, 0, stream>>>(x, conv_w, conv_b, centers, widths,
                                             down_w, down_b, out);
}